// Round 1
// baseline (481.358 us; speedup 1.0000x reference)
//
#include <hip/hip_runtime.h>

#define SEQ 2048
#define HD 768
#define NBATCH 8

typedef __attribute__((ext_vector_type(4))) float f32x4;
typedef __attribute__((ext_vector_type(8))) short s16x8;

__device__ __forceinline__ unsigned short f2bf(float f) {
  unsigned int u = __builtin_bit_cast(unsigned int, f);
  u += 0x7fffu + ((u >> 16) & 1u);
  return (unsigned short)(u >> 16);
}
__device__ __forceinline__ float bf2f(unsigned short h) {
  unsigned int u = ((unsigned int)h) << 16;
  return __builtin_bit_cast(float, u);
}

typedef const __attribute__((address_space(1))) void gas_void;
typedef __attribute__((address_space(3))) void las_void;

__device__ __forceinline__ void gload_lds16(const void* g, void* l) {
  __builtin_amdgcn_global_load_lds((gas_void*)g, (las_void*)l, 16, 0, 0);
}

// ---- GEMM building blocks ---------------------------------------------------
// LDS tile: 128 rows x 64 bf16 cols (128 B/row). Physical layout XOR-swizzled:
//   phys = row*128 + (cb ^ ((row&7)<<4))   (G4 swizzle; staging pre-swizzles the
//   global SOURCE so global_load_lds' linear dest lands correctly — rule #21)

// stage 128x64-bf16 tile from global (row-major, ldgB bytes per row)
__device__ __forceinline__ void stage_b16(const unsigned char* g, size_t ldgB,
                                          unsigned char* lds, int wid, int lane) {
#pragma unroll
  for (int c = 0; c < 4; ++c) {
    int f0 = (wid * 4 + c) * 1024;                 // wave-uniform LDS base
    int row = (f0 >> 7) + (lane >> 3);             // 8 rows per 1024B call
    int cb = (((lane & 7) ^ (lane >> 3)) & 7) << 4; // inverse-swizzled src col
    gload_lds16(g + (size_t)row * ldgB + cb, lds + f0);
  }
}

// stage 128x64 tile from f32 global, converting to bf16, reg-staged ds_write
__device__ __forceinline__ void stage_f32(const float* g, int ldg,
                                          unsigned char* lds, int tid) {
#pragma unroll
  for (int c = 0; c < 4; ++c) {
    int t = c * 256 + tid;
    int row = t >> 3;
    int colE = (t & 7) * 8;
    const float4* gp = (const float4*)(g + (size_t)row * ldg + colE);
    float4 a = gp[0], b = gp[1];
    s16x8 v;
    v[0] = (short)f2bf(a.x); v[1] = (short)f2bf(a.y);
    v[2] = (short)f2bf(a.z); v[3] = (short)f2bf(a.w);
    v[4] = (short)f2bf(b.x); v[5] = (short)f2bf(b.y);
    v[6] = (short)f2bf(b.z); v[7] = (short)f2bf(b.w);
    int phys = row * 128 + ((colE * 2) ^ ((row & 7) << 4));
    *(s16x8*)(lds + phys) = v;
  }
}

// 4 waves, wave (wr,wc) owns 64x64; 4x4 frags of 16x16, BK=64 (2 k-substeps)
__device__ __forceinline__ void tile_mfma(const unsigned char* ldsA,
                                          const unsigned char* ldsB,
                                          int wr, int wc, int lr, int lg,
                                          f32x4 acc[4][4]) {
  int aswz = (lr & 7) << 4;
#pragma unroll
  for (int ks = 0; ks < 2; ++ks) {
    int cb = (ks * 64 + lg * 16) ^ aswz;
    s16x8 af[4], bfv[4];
#pragma unroll
    for (int i = 0; i < 4; ++i)
      af[i] = *(const s16x8*)(ldsA + (wr * 64 + i * 16 + lr) * 128 + cb);
#pragma unroll
    for (int i = 0; i < 4; ++i)
      bfv[i] = *(const s16x8*)(ldsB + (wc * 64 + i * 16 + lr) * 128 + cb);
#pragma unroll
    for (int mi = 0; mi < 4; ++mi)
#pragma unroll
      for (int ni = 0; ni < 4; ++ni)
        acc[mi][ni] = __builtin_amdgcn_mfma_f32_16x16x32_bf16(
            af[mi], bfv[ni], acc[mi][ni], 0, 0, 0);
  }
}

#define GEMM_PROLOGUE()                                              \
  __shared__ unsigned char lds[32768];                               \
  unsigned char* ldsA = lds;                                         \
  unsigned char* ldsB = lds + 16384;                                 \
  int tid = threadIdx.x, lane = tid & 63, wid = tid >> 6;            \
  int lr = lane & 15, lg = lane >> 4, wr = wid >> 1, wc = wid & 1;   \
  f32x4 acc[4][4];                                                   \
  {                                                                  \
    f32x4 zz = {0.f, 0.f, 0.f, 0.f};                                 \
    for (int a_ = 0; a_ < 4; ++a_)                                   \
      for (int b_ = 0; b_ < 4; ++b_) acc[a_][b_] = zz;               \
  }                                                                  \
  (void)tid;

// ---- kernel 1: weight transpose+convert  Wt[n][k] = bf16(W[k][n]) ----------
__global__ void prep_weights(const float* __restrict__ Wq, const float* __restrict__ Wk,
                             const float* __restrict__ Wv, const float* __restrict__ Wo,
                             unsigned short* __restrict__ Wt) {
  int mat = blockIdx.y;
  const float* W = mat == 0 ? Wq : mat == 1 ? Wk : mat == 2 ? Wv : Wo;
  unsigned short* dst = Wt + (size_t)mat * HD * HD;
  int i = blockIdx.x * 256 + threadIdx.x;
  if (i < HD * HD) {
    int n = i / HD, k = i % HD;
    dst[i] = f2bf(W[(size_t)k * HD + n]);
  }
}

// ---- kernel 2: QKV projection (z: 0=Q,1=K,2=V-transposed) ------------------
__global__ __launch_bounds__(256, 2) void qkv_gemm(
    const float* __restrict__ X, const unsigned short* __restrict__ Wt,
    const float* __restrict__ bq, const float* __restrict__ bk,
    const float* __restrict__ bv, unsigned short* __restrict__ Q,
    unsigned short* __restrict__ K, unsigned short* __restrict__ Vt) {
  int which = blockIdx.z;
  const unsigned short* W = Wt + (size_t)which * HD * HD;
  const float* bias = which == 0 ? bq : which == 1 ? bk : bv;
  int m0 = blockIdx.y * 128, n0 = blockIdx.x * 128;
  GEMM_PROLOGUE();
  for (int kt = 0; kt < HD / 64; ++kt) {
    stage_f32(X + (size_t)m0 * HD + kt * 64, HD, ldsA, tid);
    stage_b16((const unsigned char*)W + ((size_t)n0 * HD + kt * 64) * 2,
              HD * 2, ldsB, wid, lane);
    __syncthreads();
    tile_mfma(ldsA, ldsB, wr, wc, lr, lg, acc);
    __syncthreads();
  }
  if (which < 2) {
    unsigned short* out = which == 0 ? Q : K;
#pragma unroll
    for (int mi = 0; mi < 4; ++mi)
#pragma unroll
      for (int ni = 0; ni < 4; ++ni) {
        int col = n0 + wc * 64 + ni * 16 + lr;
        float bb = bias[col];
#pragma unroll
        for (int j = 0; j < 4; ++j) {
          int row = m0 + wr * 64 + mi * 16 + lg * 4 + j;
          out[(size_t)row * HD + col] = f2bf(acc[mi][ni][j] + bb);
        }
      }
  } else {
#pragma unroll
    for (int mi = 0; mi < 4; ++mi)
#pragma unroll
      for (int ni = 0; ni < 4; ++ni) {
        int col = n0 + wc * 64 + ni * 16 + lr;
        float bb = bias[col];
#pragma unroll
        for (int j = 0; j < 4; ++j) {
          int row = m0 + wr * 64 + mi * 16 + lg * 4 + j;
          int b = row >> 11, s = row & (SEQ - 1);
          Vt[(size_t)b * HD * SEQ + (size_t)col * SEQ + s] =
              f2bf(acc[mi][ni][j] + bb);
        }
      }
  }
}

// ---- kernel 3: scores = scale * Q @ K^T  (per batch, bf16 out) -------------
__global__ __launch_bounds__(256, 2) void scores_gemm(
    const unsigned short* __restrict__ Q, const unsigned short* __restrict__ K,
    unsigned short* __restrict__ S, int b0) {
  int z = blockIdx.z, batch = b0 + z;
  const unsigned char* Qb = (const unsigned char*)(Q + (size_t)batch * SEQ * HD);
  const unsigned char* Kb = (const unsigned char*)(K + (size_t)batch * SEQ * HD);
  unsigned short* Sout = S + (size_t)z * SEQ * SEQ;
  int m0 = blockIdx.y * 128, n0 = blockIdx.x * 128;
  GEMM_PROLOGUE();
  for (int kt = 0; kt < HD / 64; ++kt) {
    stage_b16(Qb + ((size_t)m0 * HD + kt * 64) * 2, HD * 2, ldsA, wid, lane);
    stage_b16(Kb + ((size_t)n0 * HD + kt * 64) * 2, HD * 2, ldsB, wid, lane);
    __syncthreads();
    tile_mfma(ldsA, ldsB, wr, wc, lr, lg, acc);
    __syncthreads();
  }
  const float scale = 0.036084391824351615f;  // 1/sqrt(768)
#pragma unroll
  for (int mi = 0; mi < 4; ++mi)
#pragma unroll
    for (int ni = 0; ni < 4; ++ni) {
      int col = n0 + wc * 64 + ni * 16 + lr;
#pragma unroll
      for (int j = 0; j < 4; ++j) {
        int row = m0 + wr * 64 + mi * 16 + lg * 4 + j;
        Sout[(size_t)row * SEQ + col] = f2bf(acc[mi][ni][j] * scale);
      }
    }
}

// ---- kernel 4: masked softmax over key dim, in place on S ------------------
__global__ __launch_bounds__(256) void softmax_kernel(
    unsigned short* __restrict__ S, const int* __restrict__ mask, int b0) {
  int z = blockIdx.y, batch = b0 + z;
  int r = blockIdx.x;
  unsigned short* row = S + ((size_t)z * SEQ + r) * SEQ;
  const int* mrow = mask + (size_t)batch * SEQ;
  int tid = threadIdx.x, lane = tid & 63, wid = tid >> 6;
  int t0 = tid * 8;
  s16x8 sv = *(const s16x8*)(row + t0);
  int4 ma = *(const int4*)(mrow + t0);
  int4 mb = *(const int4*)(mrow + t0 + 4);
  int mk[8] = {ma.x, ma.y, ma.z, ma.w, mb.x, mb.y, mb.z, mb.w};
  float v[8];
  float mx = -1e30f;
#pragma unroll
  for (int j = 0; j < 8; ++j) {
    float x = bf2f((unsigned short)sv[j]);
    v[j] = mk[j] ? x : -1e30f;
    mx = fmaxf(mx, v[j]);
  }
#pragma unroll
  for (int o = 32; o; o >>= 1) mx = fmaxf(mx, __shfl_xor(mx, o));
  __shared__ float red[8];
  if (lane == 0) red[wid] = mx;
  __syncthreads();
  mx = fmaxf(fmaxf(red[0], red[1]), fmaxf(red[2], red[3]));
  float sum = 0.f;
  float e[8];
#pragma unroll
  for (int j = 0; j < 8; ++j) {
    e[j] = mk[j] ? __expf(v[j] - mx) : 0.f;
    sum += e[j];
  }
#pragma unroll
  for (int o = 32; o; o >>= 1) sum += __shfl_xor(sum, o);
  if (lane == 0) red[4 + wid] = sum;
  __syncthreads();
  sum = red[4] + red[5] + red[6] + red[7];
  float inv = sum > 0.f ? 1.f / sum : 0.f;
  s16x8 pv;
#pragma unroll
  for (int j = 0; j < 8; ++j) pv[j] = (short)f2bf(e[j] * inv);
  *(s16x8*)(row + t0) = pv;
}

// ---- kernel 5: ctx = P @ V  (B staged from V-transposed) -------------------
__global__ __launch_bounds__(256, 2) void pv_gemm(
    const unsigned short* __restrict__ P, const unsigned short* __restrict__ Vt,
    unsigned short* __restrict__ ctx, int b0) {
  int z = blockIdx.z, batch = b0 + z;
  const unsigned char* Pb = (const unsigned char*)(P + (size_t)z * SEQ * SEQ);
  const unsigned char* Vb = (const unsigned char*)(Vt + (size_t)batch * HD * SEQ);
  int m0 = blockIdx.y * 128, n0 = blockIdx.x * 128;
  GEMM_PROLOGUE();
  for (int kt = 0; kt < SEQ / 64; ++kt) {
    stage_b16(Pb + ((size_t)m0 * SEQ + kt * 64) * 2, SEQ * 2, ldsA, wid, lane);
    stage_b16(Vb + ((size_t)n0 * SEQ + kt * 64) * 2, SEQ * 2, ldsB, wid, lane);
    __syncthreads();
    tile_mfma(ldsA, ldsB, wr, wc, lr, lg, acc);
    __syncthreads();
  }
#pragma unroll
  for (int mi = 0; mi < 4; ++mi)
#pragma unroll
    for (int ni = 0; ni < 4; ++ni) {
      int col = n0 + wc * 64 + ni * 16 + lr;
#pragma unroll
      for (int j = 0; j < 4; ++j) {
        int row = m0 + wr * 64 + mi * 16 + lg * 4 + j;
        ctx[((size_t)batch * SEQ + row) * HD + col] = f2bf(acc[mi][ni][j]);
      }
    }
}

// ---- kernel 6: h = ctx @ Wo + bo + X  (f32 to d_out) -----------------------
__global__ __launch_bounds__(256, 2) void outproj_gemm(
    const unsigned short* __restrict__ ctx, const unsigned short* __restrict__ Wto,
    const float* __restrict__ bo, const float* __restrict__ X,
    float* __restrict__ out) {
  int m0 = blockIdx.y * 128, n0 = blockIdx.x * 128;
  GEMM_PROLOGUE();
  for (int kt = 0; kt < HD / 64; ++kt) {
    stage_b16((const unsigned char*)ctx + ((size_t)m0 * HD + kt * 64) * 2,
              HD * 2, ldsA, wid, lane);
    stage_b16((const unsigned char*)Wto + ((size_t)n0 * HD + kt * 64) * 2,
              HD * 2, ldsB, wid, lane);
    __syncthreads();
    tile_mfma(ldsA, ldsB, wr, wc, lr, lg, acc);
    __syncthreads();
  }
#pragma unroll
  for (int mi = 0; mi < 4; ++mi)
#pragma unroll
    for (int ni = 0; ni < 4; ++ni) {
      int col = n0 + wc * 64 + ni * 16 + lr;
      float bb = bo[col];
#pragma unroll
      for (int j = 0; j < 4; ++j) {
        int row = m0 + wr * 64 + mi * 16 + lg * 4 + j;
        size_t idx = (size_t)row * HD + col;
        out[idx] = acc[mi][ni][j] + bb + X[idx];
      }
    }
}

// ---- kernel 7: LayerNorm in place on d_out ---------------------------------
__global__ __launch_bounds__(256) void ln_kernel(float* __restrict__ out,
                                                 const float* __restrict__ gamma,
                                                 const float* __restrict__ beta) {
  int r = blockIdx.x;
  float* row = out + (size_t)r * HD;
  int tid = threadIdx.x, lane = tid & 63, wid = tid >> 6;
  float4 x = {0.f, 0.f, 0.f, 0.f};
  if (tid < 192) x = *(const float4*)(row + tid * 4);
  float s = x.x + x.y + x.z + x.w;
  float q = x.x * x.x + x.y * x.y + x.z * x.z + x.w * x.w;
#pragma unroll
  for (int o = 32; o; o >>= 1) {
    s += __shfl_xor(s, o);
    q += __shfl_xor(q, o);
  }
  __shared__ float red[8];
  if (lane == 0) { red[wid] = s; red[4 + wid] = q; }
  __syncthreads();
  s = red[0] + red[1] + red[2] + red[3];
  q = red[4] + red[5] + red[6] + red[7];
  float mu = s * (1.f / 768.f);
  float var = q * (1.f / 768.f) - mu * mu;
  float rstd = rsqrtf(var + 1e-12f);
  if (tid < 192) {
    float4 g = *(const float4*)(gamma + tid * 4);
    float4 b = *(const float4*)(beta + tid * 4);
    float4 y;
    y.x = (x.x - mu) * rstd * g.x + b.x;
    y.y = (x.y - mu) * rstd * g.y + b.y;
    y.z = (x.z - mu) * rstd * g.z + b.z;
    y.w = (x.w - mu) * rstd * g.w + b.w;
    *(float4*)(row + tid * 4) = y;
  }
}

// ---- host ------------------------------------------------------------------
extern "C" void kernel_launch(void* const* d_in, const int* in_sizes, int n_in,
                              void* d_out, int out_size, void* d_ws, size_t ws_size,
                              hipStream_t stream) {
  const float* X = (const float*)d_in[0];
  const int* mask = (const int*)d_in[1];
  const float* Wq = (const float*)d_in[2];
  const float* bq = (const float*)d_in[3];
  const float* Wk = (const float*)d_in[4];
  const float* bk = (const float*)d_in[5];
  const float* Wv = (const float*)d_in[6];
  const float* bv = (const float*)d_in[7];
  const float* Wo = (const float*)d_in[8];
  const float* bo = (const float*)d_in[9];
  const float* gamma = (const float*)d_in[10];
  const float* beta = (const float*)d_in[11];
  float* out = (float*)d_out;

  char* ws = (char*)d_ws;
  size_t off = 0;
  auto alloc = [&](size_t b) {
    void* p = ws + off;
    off += (b + 255) & ~(size_t)255;
    return p;
  };
  unsigned short* Wt = (unsigned short*)alloc((size_t)4 * HD * HD * 2);
  unsigned short* Q = (unsigned short*)alloc((size_t)NBATCH * SEQ * HD * 2);
  unsigned short* K = (unsigned short*)alloc((size_t)NBATCH * SEQ * HD * 2);
  unsigned short* Vt = (unsigned short*)alloc((size_t)NBATCH * SEQ * HD * 2);
  // batched P if workspace allows, else per-batch chunks
  int nchunk = (ws_size >= off + (size_t)NBATCH * SEQ * SEQ * 2) ? NBATCH : 1;
  unsigned short* Sbuf = (unsigned short*)alloc((size_t)nchunk * SEQ * SEQ * 2);
  unsigned short* ctx = Q;  // Q is dead once all scores are computed (per batch)

  prep_weights<<<dim3((HD * HD + 255) / 256, 4), 256, 0, stream>>>(Wq, Wk, Wv, Wo, Wt);
  qkv_gemm<<<dim3(HD / 128, NBATCH * SEQ / 128, 3), 256, 0, stream>>>(
      X, Wt, bq, bk, bv, Q, K, Vt);
  for (int b0 = 0; b0 < NBATCH; b0 += nchunk) {
    scores_gemm<<<dim3(SEQ / 128, SEQ / 128, nchunk), 256, 0, stream>>>(Q, K, Sbuf, b0);
    softmax_kernel<<<dim3(SEQ, nchunk), 256, 0, stream>>>(Sbuf, mask, b0);
    pv_gemm<<<dim3(HD / 128, SEQ / 128, nchunk), 256, 0, stream>>>(Sbuf, Vt, ctx, b0);
  }
  outproj_gemm<<<dim3(HD / 128, NBATCH * SEQ / 128), 256, 0, stream>>>(
      ctx, Wt + (size_t)3 * HD * HD, bo, X, out);
  ln_kernel<<<NBATCH * SEQ, 256, 0, stream>>>(out, gamma, beta);
}

// Round 3
// 376.490 us; speedup vs baseline: 1.2785x; 1.2785x over previous
//
#include <hip/hip_runtime.h>

#define SEQ 2048
#define HD 768
#define NBATCH 8

typedef __attribute__((ext_vector_type(4))) float f32x4;
typedef __attribute__((ext_vector_type(8))) short s16x8;

__device__ __forceinline__ unsigned short f2bf(float f) {
  unsigned int u = __builtin_bit_cast(unsigned int, f);
  u += 0x7fffu + ((u >> 16) & 1u);
  return (unsigned short)(u >> 16);
}
__device__ __forceinline__ float bf2f(unsigned short h) {
  unsigned int u = ((unsigned int)h) << 16;
  return __builtin_bit_cast(float, u);
}

typedef const __attribute__((address_space(1))) void gas_void;
typedef __attribute__((address_space(3))) void las_void;

__device__ __forceinline__ void gload_lds16(const void* g, void* l) {
  __builtin_amdgcn_global_load_lds((gas_void*)g, (las_void*)l, 16, 0, 0);
}

// bijective XCD-chunk swizzle; requires nwg % 8 == 0
__device__ __forceinline__ int xcd_swz(int f, int nwg) {
  int q = nwg >> 3;
  return (f & 7) * q + (f >> 3);
}

// ---- GEMM building blocks ---------------------------------------------------
// LDS tile: 128 rows x 64 bf16 cols (128 B/row), XOR-swizzled:
//   phys = row*128 + (cb ^ ((row&7)<<4)); staging pre-swizzles the global
//   SOURCE column so global_load_lds' linear dest lands correctly (rule #21).

__device__ __forceinline__ void stage_b16(const unsigned char* g, size_t ldgB,
                                          unsigned char* lds, int wid, int lane) {
#pragma unroll
  for (int c = 0; c < 4; ++c) {
    int f0 = (wid * 4 + c) * 1024;                  // wave-uniform LDS base
    int row = (f0 >> 7) + (lane >> 3);              // 8 rows per 1024B call
    int cb = (((lane & 7) ^ (lane >> 3)) & 7) << 4; // inverse-swizzled src col
    gload_lds16(g + (size_t)row * ldgB + cb, lds + f0);
  }
}

// 4 waves, wave (wr,wc) owns 64x64; 4x4 frags of 16x16, BK=64 (2 k-substeps)
__device__ __forceinline__ void tile_mfma(const unsigned char* ldsA,
                                          const unsigned char* ldsB,
                                          int wr, int wc, int lr, int lg,
                                          f32x4 acc[4][4]) {
  int aswz = (lr & 7) << 4;
#pragma unroll
  for (int ks = 0; ks < 2; ++ks) {
    int cb = (ks * 64 + lg * 16) ^ aswz;
    s16x8 af[4], bfv[4];
#pragma unroll
    for (int i = 0; i < 4; ++i)
      af[i] = *(const s16x8*)(ldsA + (wr * 64 + i * 16 + lr) * 128 + cb);
#pragma unroll
    for (int i = 0; i < 4; ++i)
      bfv[i] = *(const s16x8*)(ldsB + (wc * 64 + i * 16 + lr) * 128 + cb);
#pragma unroll
    for (int mi = 0; mi < 4; ++mi)
#pragma unroll
      for (int ni = 0; ni < 4; ++ni)
        acc[mi][ni] = __builtin_amdgcn_mfma_f32_16x16x32_bf16(
            af[mi], bfv[ni], acc[mi][ni], 0, 0, 0);
  }
}

#define GEMM_PROLOGUE()                                              \
  __shared__ unsigned char lds[32768];                               \
  unsigned char* ldsA = lds;                                         \
  unsigned char* ldsB = lds + 16384;                                 \
  int tid = threadIdx.x, lane = tid & 63, wid = tid >> 6;            \
  int lr = lane & 15, lg = lane >> 4, wr = wid >> 1, wc = wid & 1;   \
  f32x4 acc[4][4];                                                   \
  {                                                                  \
    f32x4 zz = {0.f, 0.f, 0.f, 0.f};                                 \
    for (int a_ = 0; a_ < 4; ++a_)                                   \
      for (int b_ = 0; b_ < 4; ++b_) acc[a_][b_] = zz;               \
  }                                                                  \
  (void)tid;

// ---- prep: LDS-tiled weight transpose+convert  Wt[n][k] = bf16(W[k][n]) ----
__global__ __launch_bounds__(256) void prep_weights(
    const float* __restrict__ Wq, const float* __restrict__ Wk,
    const float* __restrict__ Wv, const float* __restrict__ Wo,
    unsigned short* __restrict__ Wt) {
  int mat = blockIdx.z;
  const float* W = mat == 0 ? Wq : mat == 1 ? Wk : mat == 2 ? Wv : Wo;
  unsigned short* dst = Wt + (size_t)mat * HD * HD;
  int n0 = blockIdx.x * 64, k0 = blockIdx.y * 64;
  __shared__ float t[64][65];
  int tid = threadIdx.x;
  int c4 = (tid & 15) * 4, r = tid >> 4;  // r in 0..15
#pragma unroll
  for (int p = 0; p < 4; ++p) {
    int kr = r + p * 16;
    float4 v = *(const float4*)(W + (size_t)(k0 + kr) * HD + n0 + c4);
    t[kr][c4 + 0] = v.x; t[kr][c4 + 1] = v.y;
    t[kr][c4 + 2] = v.z; t[kr][c4 + 3] = v.w;
  }
  __syncthreads();
#pragma unroll
  for (int p = 0; p < 4; ++p) {
    int nr = r + p * 16;
    ushort4 o;
    o.x = f2bf(t[c4 + 0][nr]); o.y = f2bf(t[c4 + 1][nr]);
    o.z = f2bf(t[c4 + 2][nr]); o.w = f2bf(t[c4 + 3][nr]);
    *(ushort4*)(dst + (size_t)(n0 + nr) * HD + k0 + c4) = o;
  }
}

// ---- prep: X f32 -> bf16 ----------------------------------------------------
__global__ __launch_bounds__(256) void prep_x(const float* __restrict__ X,
                                              unsigned short* __restrict__ Xb) {
  size_t i = ((size_t)blockIdx.x * 256 + threadIdx.x) * 8;
  const float4* gp = (const float4*)(X + i);
  float4 a = gp[0], b = gp[1];
  s16x8 v;
  v[0] = (short)f2bf(a.x); v[1] = (short)f2bf(a.y);
  v[2] = (short)f2bf(a.z); v[3] = (short)f2bf(a.w);
  v[4] = (short)f2bf(b.x); v[5] = (short)f2bf(b.y);
  v[6] = (short)f2bf(b.z); v[7] = (short)f2bf(b.w);
  *(s16x8*)(Xb + i) = v;
}

// ---- kernel 2: QKV projection (z: 0=Q,1=K,2=V-transposed) ------------------
__global__ __launch_bounds__(256, 4) void qkv_gemm(
    const unsigned short* __restrict__ Xb, const unsigned short* __restrict__ Wt,
    const float* __restrict__ bq, const float* __restrict__ bk,
    const float* __restrict__ bv, unsigned short* __restrict__ Q,
    unsigned short* __restrict__ K, unsigned short* __restrict__ Vt) {
  int which = blockIdx.z;
  const unsigned short* W = Wt + (size_t)which * HD * HD;
  const float* bias = which == 0 ? bq : which == 1 ? bk : bv;
  int f = xcd_swz(blockIdx.x + 6 * blockIdx.y, 6 * (NBATCH * SEQ / 128));
  int n0 = (f % 6) * 128, m0 = (f / 6) * 128;
  GEMM_PROLOGUE();
  for (int kt = 0; kt < HD / 64; ++kt) {
    stage_b16((const unsigned char*)Xb + ((size_t)m0 * HD + kt * 64) * 2,
              HD * 2, ldsA, wid, lane);
    stage_b16((const unsigned char*)W + ((size_t)n0 * HD + kt * 64) * 2,
              HD * 2, ldsB, wid, lane);
    __syncthreads();
    tile_mfma(ldsA, ldsB, wr, wc, lr, lg, acc);
    __syncthreads();
  }
  if (which < 2) {
    unsigned short* out = which == 0 ? Q : K;
#pragma unroll
    for (int mi = 0; mi < 4; ++mi)
#pragma unroll
      for (int ni = 0; ni < 4; ++ni) {
        int col = n0 + wc * 64 + ni * 16 + lr;
        float bb = bias[col];
#pragma unroll
        for (int j = 0; j < 4; ++j) {
          int row = m0 + wr * 64 + mi * 16 + lg * 4 + j;
          out[(size_t)row * HD + col] = f2bf(acc[mi][ni][j] + bb);
        }
      }
  } else {
#pragma unroll
    for (int mi = 0; mi < 4; ++mi)
#pragma unroll
      for (int ni = 0; ni < 4; ++ni) {
        int col = n0 + wc * 64 + ni * 16 + lr;
        float bb = bias[col];
#pragma unroll
        for (int j = 0; j < 4; ++j) {
          int row = m0 + wr * 64 + mi * 16 + lg * 4 + j;
          int b = row >> 11, s = row & (SEQ - 1);
          Vt[(size_t)b * HD * SEQ + (size_t)col * SEQ + s] =
              f2bf(acc[mi][ni][j] + bb);
        }
      }
  }
}

// ---- kernel 3: scores = scale * Q @ K^T  (per batch, bf16 out) -------------
__global__ __launch_bounds__(256, 4) void scores_gemm(
    const unsigned short* __restrict__ Q, const unsigned short* __restrict__ K,
    unsigned short* __restrict__ S, int b0) {
  int z = blockIdx.z, batch = b0 + z;
  const unsigned char* Qb = (const unsigned char*)(Q + (size_t)batch * SEQ * HD);
  const unsigned char* Kb = (const unsigned char*)(K + (size_t)batch * SEQ * HD);
  unsigned short* Sout = S + (size_t)z * SEQ * SEQ;
  int f = xcd_swz(blockIdx.x + 16 * blockIdx.y, 256);
  int n0 = (f % 16) * 128, m0 = (f / 16) * 128;
  GEMM_PROLOGUE();
  for (int kt = 0; kt < HD / 64; ++kt) {
    stage_b16(Qb + ((size_t)m0 * HD + kt * 64) * 2, HD * 2, ldsA, wid, lane);
    stage_b16(Kb + ((size_t)n0 * HD + kt * 64) * 2, HD * 2, ldsB, wid, lane);
    __syncthreads();
    tile_mfma(ldsA, ldsB, wr, wc, lr, lg, acc);
    __syncthreads();
  }
  const float scale = 0.036084391824351615f;  // 1/sqrt(768)
#pragma unroll
  for (int mi = 0; mi < 4; ++mi)
#pragma unroll
    for (int ni = 0; ni < 4; ++ni) {
      int col = n0 + wc * 64 + ni * 16 + lr;
#pragma unroll
      for (int j = 0; j < 4; ++j) {
        int row = m0 + wr * 64 + mi * 16 + lg * 4 + j;
        Sout[(size_t)row * SEQ + col] = f2bf(acc[mi][ni][j] * scale);
      }
    }
}

// ---- kernel 4: masked softmax over key dim, in place on S ------------------
__global__ __launch_bounds__(256) void softmax_kernel(
    unsigned short* __restrict__ S, const int* __restrict__ mask, int b0) {
  int z = blockIdx.y, batch = b0 + z;
  int r = blockIdx.x;
  unsigned short* row = S + ((size_t)z * SEQ + r) * SEQ;
  const int* mrow = mask + (size_t)batch * SEQ;
  int tid = threadIdx.x, lane = tid & 63, wid = tid >> 6;
  int t0 = tid * 8;
  s16x8 sv = *(const s16x8*)(row + t0);
  int4 ma = *(const int4*)(mrow + t0);
  int4 mb = *(const int4*)(mrow + t0 + 4);
  int mk[8] = {ma.x, ma.y, ma.z, ma.w, mb.x, mb.y, mb.z, mb.w};
  float v[8];
  float mx = -1e30f;
#pragma unroll
  for (int j = 0; j < 8; ++j) {
    float x = bf2f((unsigned short)sv[j]);
    v[j] = mk[j] ? x : -1e30f;
    mx = fmaxf(mx, v[j]);
  }
#pragma unroll
  for (int o = 32; o; o >>= 1) mx = fmaxf(mx, __shfl_xor(mx, o));
  __shared__ float red[8];
  if (lane == 0) red[wid] = mx;
  __syncthreads();
  mx = fmaxf(fmaxf(red[0], red[1]), fmaxf(red[2], red[3]));
  float sum = 0.f;
  float e[8];
#pragma unroll
  for (int j = 0; j < 8; ++j) {
    e[j] = mk[j] ? __expf(v[j] - mx) : 0.f;
    sum += e[j];
  }
#pragma unroll
  for (int o = 32; o; o >>= 1) sum += __shfl_xor(sum, o);
  if (lane == 0) red[4 + wid] = sum;
  __syncthreads();
  sum = red[4] + red[5] + red[6] + red[7];
  float inv = sum > 0.f ? 1.f / sum : 0.f;
  s16x8 pv;
#pragma unroll
  for (int j = 0; j < 8; ++j) pv[j] = (short)f2bf(e[j] * inv);
  *(s16x8*)(row + t0) = pv;
}

// ---- kernel 5: ctx = P @ V  (B staged from V-transposed) -------------------
__global__ __launch_bounds__(256, 4) void pv_gemm(
    const unsigned short* __restrict__ P, const unsigned short* __restrict__ Vt,
    unsigned short* __restrict__ ctx, int b0) {
  int z = blockIdx.z, batch = b0 + z;
  const unsigned char* Pb = (const unsigned char*)(P + (size_t)z * SEQ * SEQ);
  const unsigned char* Vb = (const unsigned char*)(Vt + (size_t)batch * HD * SEQ);
  int f = xcd_swz(blockIdx.x + 6 * blockIdx.y, 6 * (SEQ / 128));
  int n0 = (f % 6) * 128, m0 = (f / 6) * 128;
  GEMM_PROLOGUE();
  for (int kt = 0; kt < SEQ / 64; ++kt) {
    stage_b16(Pb + ((size_t)m0 * SEQ + kt * 64) * 2, SEQ * 2, ldsA, wid, lane);
    stage_b16(Vb + ((size_t)n0 * SEQ + kt * 64) * 2, SEQ * 2, ldsB, wid, lane);
    __syncthreads();
    tile_mfma(ldsA, ldsB, wr, wc, lr, lg, acc);
    __syncthreads();
  }
#pragma unroll
  for (int mi = 0; mi < 4; ++mi)
#pragma unroll
    for (int ni = 0; ni < 4; ++ni) {
      int col = n0 + wc * 64 + ni * 16 + lr;
#pragma unroll
      for (int j = 0; j < 4; ++j) {
        int row = m0 + wr * 64 + mi * 16 + lg * 4 + j;
        ctx[((size_t)batch * SEQ + row) * HD + col] = f2bf(acc[mi][ni][j]);
      }
    }
}

// ---- kernel 6: h = ctx @ Wo + bo + X  (f32 to d_out) -----------------------
__global__ __launch_bounds__(256, 4) void outproj_gemm(
    const unsigned short* __restrict__ ctx, const unsigned short* __restrict__ Wto,
    const float* __restrict__ bo, const float* __restrict__ X,
    float* __restrict__ out) {
  int f = xcd_swz(blockIdx.x + 6 * blockIdx.y, 6 * (NBATCH * SEQ / 128));
  int n0 = (f % 6) * 128, m0 = (f / 6) * 128;
  GEMM_PROLOGUE();
  for (int kt = 0; kt < HD / 64; ++kt) {
    stage_b16((const unsigned char*)ctx + ((size_t)m0 * HD + kt * 64) * 2,
              HD * 2, ldsA, wid, lane);
    stage_b16((const unsigned char*)Wto + ((size_t)n0 * HD + kt * 64) * 2,
              HD * 2, ldsB, wid, lane);
    __syncthreads();
    tile_mfma(ldsA, ldsB, wr, wc, lr, lg, acc);
    __syncthreads();
  }
#pragma unroll
  for (int mi = 0; mi < 4; ++mi)
#pragma unroll
    for (int ni = 0; ni < 4; ++ni) {
      int col = n0 + wc * 64 + ni * 16 + lr;
      float bb = bo[col];
#pragma unroll
      for (int j = 0; j < 4; ++j) {
        int row = m0 + wr * 64 + mi * 16 + lg * 4 + j;
        size_t idx = (size_t)row * HD + col;
        out[idx] = acc[mi][ni][j] + bb + X[idx];
      }
    }
}

// ---- kernel 7: LayerNorm in place on d_out ---------------------------------
__global__ __launch_bounds__(256) void ln_kernel(float* __restrict__ out,
                                                 const float* __restrict__ gamma,
                                                 const float* __restrict__ beta) {
  int r = blockIdx.x;
  float* row = out + (size_t)r * HD;
  int tid = threadIdx.x, lane = tid & 63, wid = tid >> 6;
  float4 x = {0.f, 0.f, 0.f, 0.f};
  if (tid < 192) x = *(const float4*)(row + tid * 4);
  float s = x.x + x.y + x.z + x.w;
  float q = x.x * x.x + x.y * x.y + x.z * x.z + x.w * x.w;
#pragma unroll
  for (int o = 32; o; o >>= 1) {
    s += __shfl_xor(s, o);
    q += __shfl_xor(q, o);
  }
  __shared__ float red[8];
  if (lane == 0) { red[wid] = s; red[4 + wid] = q; }
  __syncthreads();
  s = red[0] + red[1] + red[2] + red[3];
  q = red[4] + red[5] + red[6] + red[7];
  float mu = s * (1.f / 768.f);
  float var = q * (1.f / 768.f) - mu * mu;
  float rstd = rsqrtf(var + 1e-12f);
  if (tid < 192) {
    float4 g = *(const float4*)(gamma + tid * 4);
    float4 b = *(const float4*)(beta + tid * 4);
    float4 y;
    y.x = (x.x - mu) * rstd * g.x + b.x;
    y.y = (x.y - mu) * rstd * g.y + b.y;
    y.z = (x.z - mu) * rstd * g.z + b.z;
    y.w = (x.w - mu) * rstd * g.w + b.w;
    *(float4*)(row + tid * 4) = y;
  }
}

// ---- host ------------------------------------------------------------------
extern "C" void kernel_launch(void* const* d_in, const int* in_sizes, int n_in,
                              void* d_out, int out_size, void* d_ws, size_t ws_size,
                              hipStream_t stream) {
  const float* X = (const float*)d_in[0];
  const int* mask = (const int*)d_in[1];
  const float* Wq = (const float*)d_in[2];
  const float* bq = (const float*)d_in[3];
  const float* Wk = (const float*)d_in[4];
  const float* bk = (const float*)d_in[5];
  const float* Wv = (const float*)d_in[6];
  const float* bv = (const float*)d_in[7];
  const float* Wo = (const float*)d_in[8];
  const float* bo = (const float*)d_in[9];
  const float* gamma = (const float*)d_in[10];
  const float* beta = (const float*)d_in[11];
  float* out = (float*)d_out;

  char* ws = (char*)d_ws;
  size_t off = 0;
  auto alloc = [&](size_t b) {
    void* p = ws + off;
    off += (b + 255) & ~(size_t)255;
    return p;
  };
  unsigned short* Wt = (unsigned short*)alloc((size_t)4 * HD * HD * 2);
  unsigned short* Xb = (unsigned short*)alloc((size_t)NBATCH * SEQ * HD * 2);
  unsigned short* Q = (unsigned short*)alloc((size_t)NBATCH * SEQ * HD * 2);
  unsigned short* K = (unsigned short*)alloc((size_t)NBATCH * SEQ * HD * 2);
  unsigned short* Vt = (unsigned short*)alloc((size_t)NBATCH * SEQ * HD * 2);
  // batched P if workspace allows, else per-batch chunks
  int nchunk = (ws_size >= off + (size_t)NBATCH * SEQ * SEQ * 2) ? NBATCH : 1;
  unsigned short* Sbuf = (unsigned short*)alloc((size_t)nchunk * SEQ * SEQ * 2);
  unsigned short* ctx = Q;  // Q is dead once all scores are computed

  prep_weights<<<dim3(HD / 64, HD / 64, 4), 256, 0, stream>>>(Wq, Wk, Wv, Wo, Wt);
  prep_x<<<(NBATCH * SEQ * HD) / (256 * 8), 256, 0, stream>>>(X, Xb);
  qkv_gemm<<<dim3(HD / 128, NBATCH * SEQ / 128, 3), 256, 0, stream>>>(
      Xb, Wt, bq, bk, bv, Q, K, Vt);
  for (int b0 = 0; b0 < NBATCH; b0 += nchunk) {
    scores_gemm<<<dim3(SEQ / 128, SEQ / 128, nchunk), 256, 0, stream>>>(Q, K, Sbuf, b0);
    softmax_kernel<<<dim3(SEQ, nchunk), 256, 0, stream>>>(Sbuf, mask, b0);
    pv_gemm<<<dim3(HD / 128, SEQ / 128, nchunk), 256, 0, stream>>>(Sbuf, Vt, ctx, b0);
  }
  outproj_gemm<<<dim3(HD / 128, NBATCH * SEQ / 128), 256, 0, stream>>>(
      ctx, Wt + (size_t)3 * HD * HD, bo, X, out);
  ln_kernel<<<NBATCH * SEQ, 256, 0, stream>>>(out, gamma, beta);
}